// Round 1
// 547.393 us; speedup vs baseline: 1.0693x; 1.0693x over previous
//
#include <hip/hip_runtime.h>
#include <hip/hip_bf16.h>

#define N_NODES  50000
#define N_EDGES  800000
#define ND       64
#define ED       32
#define MSGD     128
#define HIDD     256
#define N_AGENTS 25000
#define EPAD     800064   // N_EDGES + 64 (tile padding)

typedef _Float16 f16;
typedef __attribute__((ext_vector_type(4))) _Float16 f16x4;
typedef __attribute__((ext_vector_type(8))) _Float16 f16x8;
typedef __attribute__((ext_vector_type(4))) float f32x4;
typedef unsigned short u16;
typedef unsigned int   u32;
typedef unsigned long long u64;

// ============================================================================
// pack all four weight matrices into fp16 MFMA A-fragment order.
// frag for 16x16x32: lane l, elem j <-> W[k = ks*32 + (l>>4)*8 + j][n = nt*16 + (l&15)]
// ============================================================================
__global__ __launch_bounds__(256) void pack_weights(
    const float* __restrict__ W1, const float* __restrict__ W2,
    const float* __restrict__ Wh1, const float* __restrict__ Wh2,
    f16* __restrict__ F1, f16* __restrict__ F2,
    f16* __restrict__ F3, f16* __restrict__ F4)
{
    int tid  = blockIdx.x * 256 + threadIdx.x;
    int grp  = tid >> 6, lane = tid & 63;
    const float* W; f16* D; int NT, stride, gl;
    if      (grp < 80)  { W = W1;  D = F1; NT = 16; stride = 256; gl = grp; }
    else if (grp < 144) { W = W2;  D = F2; NT = 8;  stride = 128; gl = grp - 80; }
    else if (grp < 208) { W = Wh1; D = F3; NT = 16; stride = 256; gl = grp - 144; }
    else if (grp < 336) { W = Wh2; D = F4; NT = 16; stride = 256; gl = grp - 208; }
    else return;
    int ks = gl / NT, nt = gl - ks * NT;
    int n  = nt * 16 + (lane & 15);
    int k0 = ks * 32 + (lane >> 4) * 8;
    f16* dst = D + ((size_t)gl * 64 + lane) * 8;
    #pragma unroll
    for (int j = 0; j < 8; ++j)
        dst[j] = (f16)W[(size_t)(k0 + j) * stride + n];
}

// ============================================================================
// compact: keep edges with recv < N_AGENTS; per-receiver rank via atomicAdd.
// R13: also folds in nf(f32)->nf16 conversion: exactly one float4 per thread
// (N_NODES*ND/4 == 800000 == N_EDGES, one elem per existing thread, free BW).
// ============================================================================
__global__ __launch_bounds__(256) void compact_kernel(
    const int* __restrict__ recv, const float* __restrict__ nf,
    f16* __restrict__ nf16, int* __restrict__ elist,
    int* __restrict__ rlist, int* __restrict__ rankl,
    int* __restrict__ deg, int* __restrict__ cnt)
{
    int i = blockIdx.x * 256 + threadIdx.x;
    {   // nf -> f16 (coalesced float4 read, f16x4 write)
        float4 v = ((const float4*)nf)[i];
        f16x4 h;
        h.x = (f16)v.x; h.y = (f16)v.y; h.z = (f16)v.z; h.w = (f16)v.w;
        ((f16x4*)nf16)[i] = h;
    }
    int r = recv[i];
    bool keep = (r < N_AGENTS);
    u64 m = __ballot(keep);
    int lane = threadIdx.x & 63;
    int tot = __popcll(m);
    int base = 0;
    if (lane == 0 && tot > 0) base = atomicAdd(cnt, tot);
    base = __shfl(base, 0, 64);
    if (keep) {
        int p = base + __popcll(m & ((1ull << lane) - 1ull));
        int rank = atomicAdd(&deg[r], 1);
        elist[p] = i;
        rlist[p] = r;
        rankl[p] = rank;
    }
}

// ============================================================================
// prefix: exclusive scan deg -> off[25001] (single block)
// ============================================================================
__global__ __launch_bounds__(1024) void prefix_kernel(
    const int* __restrict__ deg, int* __restrict__ off)
{
    __shared__ int part[1024];
    int t = threadIdx.x;
    int i0 = t * 25;
    int s = 0;
    #pragma unroll 1
    for (int i = 0; i < 25; ++i) {
        int idx = i0 + i;
        if (idx < N_AGENTS) s += deg[idx];
    }
    part[t] = s;
    __syncthreads();
    for (int d = 1; d < 1024; d <<= 1) {
        int v = (t >= d) ? part[t - d] : 0;
        __syncthreads();
        part[t] += v;
        __syncthreads();
    }
    int run = (t == 0) ? 0 : part[t - 1];
    #pragma unroll 1
    for (int i = 0; i < 25; ++i) {
        int idx = i0 + i;
        if (idx < N_AGENTS) {
            off[idx] = run;
            run += deg[idx];
        }
    }
    if (t == 1023) off[N_AGENTS] = part[1023];
}

// ============================================================================
// scatter (no atomics): position = off[r] + rank
// R13: additionally materializes sendb[pos]=send[eid] and recvb[pos]=r so the
// edge-MLP staging chain is coalesced-index -> single row gather (was
// eidb -> send[eid] -> nf row: 3 dependent levels).
// ============================================================================
__global__ __launch_bounds__(256) void scatter_kernel(
    const int* __restrict__ elist, const int* __restrict__ rlist,
    const int* __restrict__ rankl, const int* __restrict__ off,
    const int* __restrict__ cnt, const int* __restrict__ send,
    int* __restrict__ eidb, int* __restrict__ sendb, int* __restrict__ recvb)
{
    int n = cnt[0];
    for (int ci = blockIdx.x * 256 + threadIdx.x; ci < n; ci += gridDim.x * 256) {
        int eid = elist[ci];
        int r   = rlist[ci];
        int pos = off[r] + rankl[ci];
        eidb[pos]  = eid;
        sendb[pos] = send[eid];
        recvb[pos] = r;
    }
}

// ============================================================================
// Edge MLP — R4/R10 core with XF DOUBLE-BUFFER (R11) + R13 staging diet:
//  - node rows gathered from pre-converted nf16 (128 B rows, f16x8/lane,
//    zero converts) via coalesced sendb/recvb index loads (1 dependent level).
//  - ef part unchanged semantics: eidb -> f32 row gather + convert (kept f32
//    to avoid +51 MB workspace for a compacted f16 copy).
//  - per-tile lane-loads 1280 -> 768; f32->f16 converts 5120 -> 1024.
// Staging loop stays rolled/variable-trip with intra-row-contiguous lanes
// (R8/R9: restructures blow FETCH to 450-514 MB — do NOT unroll/split it).
// Grid 512 (measured optimum; 1024 thrashes L2 — R12). XCD-chunked tiles.
// ============================================================================
__global__ __launch_bounds__(512, 4) void edge_mlp_mfma(
    const f16* __restrict__ nf16, const float* __restrict__ ef,
    const f16* __restrict__ F1, const f16* __restrict__ F2,
    const float* __restrict__ b1, const float* __restrict__ b2,
    const float* __restrict__ wg, const float* __restrict__ bg,
    const int* __restrict__ sendb, const int* __restrict__ recvb,
    const int* __restrict__ eidb, const int* __restrict__ cnt,
    f16* __restrict__ msg_out, float* __restrict__ evals)
{
    __shared__ __align__(16) f16 XF[2][10][64][8];  // 20 KB (double buffer)
    __shared__ __align__(16) f16 HB[16][64][8];     // 16 KB
    __shared__ __align__(16) f16 msgt[32][136];     // 8.5 KB
    __shared__ float lpart[8][32];

    const int tid  = threadIdx.x;
    const int wv   = tid >> 6;
    const int lane = tid & 63;
    const int q    = lane >> 4;
    const int li   = lane & 15;
    const int cntv   = cnt[0];
    const int ntiles = (cntv + 31) >> 5;

    // XCD-chunked tile assignment (round-robin blockIdx->XCD heuristic):
    const int xcd   = blockIdx.x & 7;
    const int bslot = blockIdx.x >> 3;
    const int tstep = gridDim.x >> 3;          // blocks per XCD
    const int T8    = (ntiles + 7) >> 3;
    const int tend  = min((xcd + 1) * T8, ntiles);
    const int t0    = xcd * T8 + bslot;

    // stationary weight fragments: W1 2 col-tiles + W2 1 col-tile per wave
    f16x8 w1[2][5], w2[8];
    #pragma unroll
    for (int ntl = 0; ntl < 2; ++ntl)
        #pragma unroll
        for (int ks = 0; ks < 5; ++ks)
            w1[ntl][ks] = *(const f16x8*)(F1 + (((size_t)(ks * 16 + 2 * wv + ntl)) * 64 + lane) * 8);
    #pragma unroll
    for (int ks = 0; ks < 8; ++ks)
        w2[ks] = *(const f16x8*)(F2 + (((size_t)(ks * 8 + wv)) * 64 + lane) * 8);

    const float4 ba  = *(const float4*)&b1[wv * 32 + q * 4];
    const float4 bb  = *(const float4*)&b1[wv * 32 + 16 + q * 4];
    const float4 bc  = *(const float4*)&b2[wv * 16 + q * 4];
    const float4 wg4 = *(const float4*)&wg[wv * 16 + q * 4];
    const float  bgv = bg[0];

    // ---- prologue: stage first tile into XF[0] ----
    if (t0 < tend) {
        const int e0p = t0 * 32;
        f16 (*XFd)[64][8] = XF[0];
        for (int idx = tid; idx < 768; idx += 512) {
            int e = idx / 24, g = idx - e * 24;
            int cp = e0p + e;
            if (g < 16) {
                int node = (g < 8) ? sendb[cp] : recvb[cp];
                f16x8 h = *(const f16x8*)(nf16 + (size_t)node * 64 + (g & 7) * 8);
                int slt = (e >> 4) * 5 + (g >> 2);
                int ln  = (e & 15) + 16 * (g & 3);
                *(f16x8*)&XFd[slt][ln][0] = h;
            } else {
                int eid = eidb[cp];
                float4 v = ((const float4*)ef)[(size_t)eid * 8 + (g - 16)];
                int k0  = 128 + (g - 16) * 4;
                int slt = (e >> 4) * 5 + 4;
                int ln  = (e & 15) + 16 * ((k0 & 31) >> 3);
                int j0  = k0 & 7;
                f16x4 h;
                h.x = (f16)v.x; h.y = (f16)v.y; h.z = (f16)v.z; h.w = (f16)v.w;
                *(f16x4*)&XFd[slt][ln][j0] = h;
            }
        }
    }
    __syncthreads();

    int p = 0;
    for (int t = t0; t < tend; t += tstep) {
        const int e0 = t * 32;
        const int tn = t + tstep;

        // ---- stage NEXT tile into XF[p^1] — no barrier before layer1 ----
        if (tn < tend) {
            const int e0n = tn * 32;
            f16 (*XFd)[64][8] = XF[p ^ 1];
            for (int idx = tid; idx < 768; idx += 512) {
                int e = idx / 24, g = idx - e * 24;
                int cp = e0n + e;
                if (g < 16) {
                    int node = (g < 8) ? sendb[cp] : recvb[cp];
                    f16x8 h = *(const f16x8*)(nf16 + (size_t)node * 64 + (g & 7) * 8);
                    int slt = (e >> 4) * 5 + (g >> 2);
                    int ln  = (e & 15) + 16 * (g & 3);
                    *(f16x8*)&XFd[slt][ln][0] = h;
                } else {
                    int eid = eidb[cp];
                    float4 v = ((const float4*)ef)[(size_t)eid * 8 + (g - 16)];
                    int k0  = 128 + (g - 16) * 4;
                    int slt = (e >> 4) * 5 + 4;
                    int ln  = (e & 15) + 16 * ((k0 & 31) >> 3);
                    int j0  = k0 & 7;
                    f16x4 h;
                    h.x = (f16)v.x; h.y = (f16)v.y; h.z = (f16)v.z; h.w = (f16)v.w;
                    *(f16x4*)&XFd[slt][ln][j0] = h;
                }
            }
        }

        // ---- layer 1: h[col][edge] = W1^T x^T (from XF[p]) ----
        f32x4 acc[2][2];   // [eh][ntl]
        acc[0][0] = f32x4{ba.x, ba.y, ba.z, ba.w}; acc[1][0] = acc[0][0];
        acc[0][1] = f32x4{bb.x, bb.y, bb.z, bb.w}; acc[1][1] = acc[0][1];
        #pragma unroll
        for (int ks = 0; ks < 5; ++ks)
            #pragma unroll
            for (int eh = 0; eh < 2; ++eh) {
                f16x8 xh = *(const f16x8*)XF[p][eh * 5 + ks][lane];
                acc[eh][0] = __builtin_amdgcn_mfma_f32_16x16x32_f16(w1[0][ks], xh, acc[eh][0], 0, 0, 0);
                acc[eh][1] = __builtin_amdgcn_mfma_f32_16x16x32_f16(w1[1][ks], xh, acc[eh][1], 0, 0, 0);
            }
        // relu + stash h as layer-2 B frags
        #pragma unroll
        for (int eh = 0; eh < 2; ++eh)
            #pragma unroll
            for (int ntl = 0; ntl < 2; ++ntl) {
                f16x4 hv;
                hv.x = (f16)fmaxf(acc[eh][ntl][0], 0.f);
                hv.y = (f16)fmaxf(acc[eh][ntl][1], 0.f);
                hv.z = (f16)fmaxf(acc[eh][ntl][2], 0.f);
                hv.w = (f16)fmaxf(acc[eh][ntl][3], 0.f);
                int l2 = li + 16 * (2 * ntl + (q >> 1));
                int j0 = (q & 1) * 4;
                *(f16x4*)&HB[eh * 8 + wv][l2][j0] = hv;
            }
        __syncthreads();   // B1: HB ready; XF[p^1] staged

        // ---- layer 2: msg[col][edge] = W2^T h^T ----
        f32x4 acc2[2];
        acc2[0] = f32x4{bc.x, bc.y, bc.z, bc.w}; acc2[1] = acc2[0];
        #pragma unroll
        for (int ks2 = 0; ks2 < 8; ++ks2)
            #pragma unroll
            for (int eh = 0; eh < 2; ++eh) {
                f16x8 hh = *(const f16x8*)HB[eh * 8 + ks2][lane];
                acc2[eh] = __builtin_amdgcn_mfma_f32_16x16x32_f16(w2[ks2], hh, acc2[eh], 0, 0, 0);
            }
        // relu + gate partial + msg stash
        {
            float pr[2];
            #pragma unroll
            for (int eh = 0; eh < 2; ++eh) {
                float v0 = fmaxf(acc2[eh][0], 0.f);
                float v1 = fmaxf(acc2[eh][1], 0.f);
                float v2 = fmaxf(acc2[eh][2], 0.f);
                float v3 = fmaxf(acc2[eh][3], 0.f);
                f16x4 mm;
                mm.x = (f16)v0; mm.y = (f16)v1; mm.z = (f16)v2; mm.w = (f16)v3;
                *(f16x4*)&msgt[eh * 16 + li][wv * 16 + q * 4] = mm;
                float pp = v0 * wg4.x + v1 * wg4.y + v2 * wg4.z + v3 * wg4.w;
                pp += __shfl_xor(pp, 16, 64);
                pp += __shfl_xor(pp, 32, 64);
                pr[eh] = pp;
            }
            if (lane < 16) {
                lpart[wv][li]      = pr[0];
                lpart[wv][16 + li] = pr[1];
            }
        }
        __syncthreads();   // B2: msgt/lpart ready

        // ---- writeback: coalesced msg rows + evals = exp(logit) ----
        {
            int row = tid >> 4, cg = tid & 15;
            *(uint4*)(msg_out + (size_t)(e0 + row) * 128 + cg * 8) =
                *(const uint4*)&msgt[row][cg * 8];
        }
        if (tid < 32) {
            float s2 = bgv;
            #pragma unroll
            for (int w = 0; w < 8; ++w) s2 += lpart[w][tid];
            evals[e0 + tid] = expf(s2);   // softmax shift-invariant; |logit|~O(5)
        }
        p ^= 1;
    }
}

// ============================================================================
// Fused CSR softmax-aggregation + agent MLP. 1024 thr, 32 receivers/block.
// Aggregation: 32 threads per receiver, 4 cols each (8 B/lane), sequential
// bucket rows. R13: 4-way software-pipelined inner loop — the rolled loop
// paid full memory latency per bucket row; 4 independent row loads/iter.
// ============================================================================
__global__ __launch_bounds__(1024, 4) void agg_agent_mfma(
    const int* __restrict__ off, const float* __restrict__ evals,
    const f16* __restrict__ msg,
    const f16* __restrict__ F3, const f16* __restrict__ F4,
    const float* __restrict__ bh1, const float* __restrict__ bh2,
    const float* __restrict__ Wout, const float* __restrict__ bout,
    float* __restrict__ out)
{
    __shared__ __align__(16) f16 XA[8][64][8];     // 8 KB
    __shared__ __align__(16) f16 HB2[16][64][8];   // 16 KB
    __shared__ float lpart[16][32];

    const int tid  = threadIdx.x;
    const int wv   = tid >> 6;
    const int lane = tid & 63;
    const int q    = lane >> 4;
    const int li   = lane & 15;
    const int a0i  = blockIdx.x * 32;

    // ---- aggregation straight into XA fragment layout ----
    {
        int g = tid >> 5, c = tid & 31;   // receiver a0i+g, cols [c*4, c*4+4)
        int r = a0i + g;
        float den = 1e-9f;
        float4 acc = make_float4(0.f, 0.f, 0.f, 0.f);
        if (r < N_AGENTS) {
            int beg = off[r], end = off[r + 1];
            const u64* mp = (const u64*)(msg + (size_t)beg * 128) + c;
            int pp = beg;
            for (; pp + 3 < end; pp += 4, mp += 128) {
                float e0 = evals[pp], e1 = evals[pp + 1];
                float e2 = evals[pp + 2], e3 = evals[pp + 3];
                u64 u0 = mp[0], u1 = mp[32], u2 = mp[64], u3 = mp[96];
                den += (e0 + e1) + (e2 + e3);
                union { u64 u; f16 h[4]; } c0, c1, c2, c3;
                c0.u = u0; c1.u = u1; c2.u = u2; c3.u = u3;
                acc.x = fmaf(e3, (float)c3.h[0], fmaf(e2, (float)c2.h[0],
                        fmaf(e1, (float)c1.h[0], fmaf(e0, (float)c0.h[0], acc.x))));
                acc.y = fmaf(e3, (float)c3.h[1], fmaf(e2, (float)c2.h[1],
                        fmaf(e1, (float)c1.h[1], fmaf(e0, (float)c0.h[1], acc.y))));
                acc.z = fmaf(e3, (float)c3.h[2], fmaf(e2, (float)c2.h[2],
                        fmaf(e1, (float)c1.h[2], fmaf(e0, (float)c0.h[2], acc.z))));
                acc.w = fmaf(e3, (float)c3.h[3], fmaf(e2, (float)c2.h[3],
                        fmaf(e1, (float)c1.h[3], fmaf(e0, (float)c0.h[3], acc.w))));
            }
            for (; pp < end; ++pp, mp += 32) {
                float e = evals[pp];
                den += e;
                union { u64 u; f16 h[4]; } cv; cv.u = *mp;
                acc.x = fmaf(e, (float)cv.h[0], acc.x);
                acc.y = fmaf(e, (float)cv.h[1], acc.y);
                acc.z = fmaf(e, (float)cv.h[2], acc.z);
                acc.w = fmaf(e, (float)cv.h[3], acc.w);
            }
        }
        float inv = 1.0f / den;
        int k0   = c * 4;
        int slot = (g >> 4) * 4 + (k0 >> 5);
        int ln   = (g & 15) + 16 * ((k0 & 31) >> 3);
        int j0   = k0 & 7;
        f16x4 h;
        h.x = (f16)(acc.x * inv); h.y = (f16)(acc.y * inv);
        h.z = (f16)(acc.z * inv); h.w = (f16)(acc.w * inv);
        *(f16x4*)&XA[slot][ln][j0] = h;
    }
    __syncthreads();

    // ---- weight fragments + layer 1 ----
    f16x8 wh1[4], wh2[8];
    #pragma unroll
    for (int ks = 0; ks < 4; ++ks)
        wh1[ks] = *(const f16x8*)(F3 + (((size_t)(ks * 16 + wv)) * 64 + lane) * 8);
    #pragma unroll
    for (int ks = 0; ks < 8; ++ks)
        wh2[ks] = *(const f16x8*)(F4 + (((size_t)(ks * 16 + wv)) * 64 + lane) * 8);

    f32x4 acc[2] = {};
    #pragma unroll
    for (int ks = 0; ks < 4; ++ks)
        #pragma unroll
        for (int eh = 0; eh < 2; ++eh) {
            f16x8 xh = *(const f16x8*)XA[eh * 4 + ks][lane];
            acc[eh] = __builtin_amdgcn_mfma_f32_16x16x32_f16(wh1[ks], xh, acc[eh], 0, 0, 0);
        }
    {
        const float4 b1v = ((const float4*)bh1)[wv * 4 + q];
        #pragma unroll
        for (int eh = 0; eh < 2; ++eh) {
            f16x4 hv;
            hv.x = (f16)fmaxf(acc[eh][0] + b1v.x, 0.f);
            hv.y = (f16)fmaxf(acc[eh][1] + b1v.y, 0.f);
            hv.z = (f16)fmaxf(acc[eh][2] + b1v.z, 0.f);
            hv.w = (f16)fmaxf(acc[eh][3] + b1v.w, 0.f);
            int l2 = li + 16 * ((wv & 1) * 2 + (q >> 1));
            int j0 = (q & 1) * 4;
            *(f16x4*)&HB2[eh * 8 + (wv >> 1)][l2][j0] = hv;
        }
    }
    __syncthreads();

    // ---- layer 2 + output partial ----
    f32x4 acc2[2] = {};
    #pragma unroll
    for (int ks2 = 0; ks2 < 8; ++ks2)
        #pragma unroll
        for (int eh = 0; eh < 2; ++eh) {
            f16x8 hh = *(const f16x8*)HB2[eh * 8 + ks2][lane];
            acc2[eh] = __builtin_amdgcn_mfma_f32_16x16x32_f16(wh2[ks2], hh, acc2[eh], 0, 0, 0);
        }
    {
        const float4 b2v = ((const float4*)bh2)[wv * 4 + q];
        const float4 wo4 = ((const float4*)Wout)[wv * 4 + q];
        float pr[2];
        #pragma unroll
        for (int eh = 0; eh < 2; ++eh) {
            float pp = fmaxf(acc2[eh][0] + b2v.x, 0.f) * wo4.x
                     + fmaxf(acc2[eh][1] + b2v.y, 0.f) * wo4.y
                     + fmaxf(acc2[eh][2] + b2v.z, 0.f) * wo4.z
                     + fmaxf(acc2[eh][3] + b2v.w, 0.f) * wo4.w;
            pp += __shfl_xor(pp, 16, 64);
            pp += __shfl_xor(pp, 32, 64);
            pr[eh] = pp;
        }
        if (lane < 16) {
            lpart[wv][li]      = pr[0];
            lpart[wv][16 + li] = pr[1];
        }
    }
    __syncthreads();

    if (tid < 32 && a0i + tid < N_AGENTS) {
        float s = bout[0];
        #pragma unroll
        for (int w = 0; w < 16; ++w) s += lpart[w][tid];
        out[a0i + tid] = tanhf(s);
    }
}

// ============================================================================
extern "C" void kernel_launch(void* const* d_in, const int* in_sizes, int n_in,
                              void* d_out, int out_size, void* d_ws, size_t ws_size,
                              hipStream_t stream)
{
    const float* nf   = (const float*)d_in[0];
    const float* ef   = (const float*)d_in[1];
    const float* W1   = (const float*)d_in[2];
    const float* b1   = (const float*)d_in[3];
    const float* W2   = (const float*)d_in[4];
    const float* b2   = (const float*)d_in[5];
    const float* wg   = (const float*)d_in[6];
    const float* bg   = (const float*)d_in[7];
    const float* Wh1  = (const float*)d_in[8];
    const float* bh1  = (const float*)d_in[9];
    const float* Wh2  = (const float*)d_in[10];
    const float* bh2  = (const float*)d_in[11];
    const float* Wout = (const float*)d_in[12];
    const float* bout = (const float*)d_in[13];
    const int*   send = (const int*)d_in[14];
    const int*   recv = (const int*)d_in[15];

    // workspace: [cnt|deg|eidb|sendb|recvb] zeroed (tail indices of the last
    // padded tile must gather row 0, not garbage), then the rest
    char* ws = (char*)d_ws;
    int* cntp   = (int*)ws;            ws += 16;
    int* deg    = (int*)ws;            ws += (size_t)N_AGENTS * 4;
    int* eidb   = (int*)ws;            ws += (size_t)EPAD * 4;
    int* sendb  = (int*)ws;            ws += (size_t)EPAD * 4;
    int* recvb  = (int*)ws;            ws += (size_t)EPAD * 4;
    size_t zero_bytes = (size_t)(ws - (char*)d_ws);
    int* elist  = (int*)ws;            ws += (size_t)EPAD * 4;
    int* rlist  = (int*)ws;            ws += (size_t)EPAD * 4;
    int* rankl  = (int*)ws;            ws += (size_t)EPAD * 4;
    int* off    = (int*)ws;            ws += (size_t)(N_AGENTS + 8) * 4;
    float* evals = (float*)ws;         ws += (size_t)EPAD * 4;
    f16* nf16   = (f16*)ws;            ws += (size_t)N_NODES * ND * 2;
    f16* F1     = (f16*)ws;            ws += (size_t)160 * 256 * 2;
    f16* F2     = (f16*)ws;            ws += (size_t)256 * 128 * 2;
    f16* F3     = (f16*)ws;            ws += (size_t)128 * 256 * 2;
    f16* F4     = (f16*)ws;            ws += (size_t)256 * 256 * 2;
    f16* msg    = (f16*)ws;

    hipMemsetAsync(d_ws, 0, zero_bytes, stream);

    pack_weights<<<84, 256, 0, stream>>>(W1, W2, Wh1, Wh2, F1, F2, F3, F4);
    compact_kernel<<<N_EDGES / 256, 256, 0, stream>>>(
        recv, nf, nf16, elist, rlist, rankl, deg, cntp);
    prefix_kernel<<<1, 1024, 0, stream>>>(deg, off);
    scatter_kernel<<<1024, 256, 0, stream>>>(
        elist, rlist, rankl, off, cntp, send, eidb, sendb, recvb);
    edge_mlp_mfma<<<512, 512, 0, stream>>>(
        nf16, ef, F1, F2, b1, b2, wg, bg, sendb, recvb, eidb, cntp, msg, evals);
    agg_agent_mfma<<<(N_AGENTS + 31) / 32, 1024, 0, stream>>>(
        off, evals, msg, F3, F4, bh1, bh2, Wout, bout, (float*)d_out);
}

// Round 2
// 415.759 us; speedup vs baseline: 1.4078x; 1.3166x over previous
//
#include <hip/hip_runtime.h>
#include <hip/hip_bf16.h>

#define N_NODES  50000
#define N_EDGES  800000
#define ND       64
#define ED       32
#define MSGD     128
#define HIDD     256
#define N_AGENTS 25000
#define EPAD     800064   // N_EDGES + 64 (tile padding)

typedef _Float16 f16;
typedef __attribute__((ext_vector_type(4))) _Float16 f16x4;
typedef __attribute__((ext_vector_type(8))) _Float16 f16x8;
typedef __attribute__((ext_vector_type(4))) float f32x4;
typedef unsigned short u16;
typedef unsigned int   u32;
typedef unsigned long long u64;

// ============================================================================
// pack all four weight matrices into fp16 MFMA A-fragment order.
// frag for 16x16x32: lane l, elem j <-> W[k = ks*32 + (l>>4)*8 + j][n = nt*16 + (l&15)]
// ============================================================================
__global__ __launch_bounds__(256) void pack_weights(
    const float* __restrict__ W1, const float* __restrict__ W2,
    const float* __restrict__ Wh1, const float* __restrict__ Wh2,
    f16* __restrict__ F1, f16* __restrict__ F2,
    f16* __restrict__ F3, f16* __restrict__ F4)
{
    int tid  = blockIdx.x * 256 + threadIdx.x;
    int grp  = tid >> 6, lane = tid & 63;
    const float* W; f16* D; int NT, stride, gl;
    if      (grp < 80)  { W = W1;  D = F1; NT = 16; stride = 256; gl = grp; }
    else if (grp < 144) { W = W2;  D = F2; NT = 8;  stride = 128; gl = grp - 80; }
    else if (grp < 208) { W = Wh1; D = F3; NT = 16; stride = 256; gl = grp - 144; }
    else if (grp < 336) { W = Wh2; D = F4; NT = 16; stride = 256; gl = grp - 208; }
    else return;
    int ks = gl / NT, nt = gl - ks * NT;
    int n  = nt * 16 + (lane & 15);
    int k0 = ks * 32 + (lane >> 4) * 8;
    f16* dst = D + ((size_t)gl * 64 + lane) * 8;
    #pragma unroll
    for (int j = 0; j < 8; ++j)
        dst[j] = (f16)W[(size_t)(k0 + j) * stride + n];
}

// ============================================================================
// R14: compact WITHOUT the single-address cnt atomic (was the 154 us serial
// chain: 12.5k waves blocking on one atomic-with-return at ~12 ns each).
// Per-receiver rank atomic only (770k ops spread over 25k addresses — they
// pipeline across L2 banks). rankb is indexed by ORIGINAL edge id; the dense
// order is recreated by scatter via off[r]+rank, and total count comes from
// off[N_AGENTS]. Also folds nf(f32)->nf16 (one float4 per thread, free BW).
// ============================================================================
__global__ __launch_bounds__(256) void compact_kernel(
    const int* __restrict__ recv, const float* __restrict__ nf,
    f16* __restrict__ nf16, int* __restrict__ rankb,
    int* __restrict__ deg)
{
    int i = blockIdx.x * 256 + threadIdx.x;
    {   // nf -> f16 (coalesced float4 read, f16x4 write)
        float4 v = ((const float4*)nf)[i];
        f16x4 h;
        h.x = (f16)v.x; h.y = (f16)v.y; h.z = (f16)v.z; h.w = (f16)v.w;
        ((f16x4*)nf16)[i] = h;
    }
    int r = recv[i];
    if (r < N_AGENTS)
        rankb[i] = atomicAdd(&deg[r], 1);
}

// ============================================================================
// prefix: exclusive scan deg -> off[25001] (single block)
// ============================================================================
__global__ __launch_bounds__(1024) void prefix_kernel(
    const int* __restrict__ deg, int* __restrict__ off)
{
    __shared__ int part[1024];
    int t = threadIdx.x;
    int i0 = t * 25;
    int s = 0;
    #pragma unroll 1
    for (int i = 0; i < 25; ++i) {
        int idx = i0 + i;
        if (idx < N_AGENTS) s += deg[idx];
    }
    part[t] = s;
    __syncthreads();
    for (int d = 1; d < 1024; d <<= 1) {
        int v = (t >= d) ? part[t - d] : 0;
        __syncthreads();
        part[t] += v;
        __syncthreads();
    }
    int run = (t == 0) ? 0 : part[t - 1];
    #pragma unroll 1
    for (int i = 0; i < 25; ++i) {
        int idx = i0 + i;
        if (idx < N_AGENTS) {
            off[idx] = run;
            run += deg[idx];
        }
    }
    if (t == 1023) off[N_AGENTS] = part[1023];
}

// ============================================================================
// scatter (no atomics): iterate ALL edges; pos = off[recv] + rankb.
// Coalesced recv/send/rankb reads; 3 scattered 4B writes for kept edges.
// ============================================================================
__global__ __launch_bounds__(256) void scatter_kernel(
    const int* __restrict__ recv, const int* __restrict__ send,
    const int* __restrict__ rankb, const int* __restrict__ off,
    int* __restrict__ eidb, int* __restrict__ sendb, int* __restrict__ recvb)
{
    int i = blockIdx.x * 256 + threadIdx.x;
    int r = recv[i];
    if (r < N_AGENTS) {
        int pos = off[r] + rankb[i];
        eidb[pos]  = i;
        sendb[pos] = send[i];
        recvb[pos] = r;
    }
}

// ============================================================================
// Edge MLP — R4/R10 core with XF DOUBLE-BUFFER (R11) + R13 staging diet:
//  - node rows gathered from pre-converted nf16 (128 B rows, f16x8/lane,
//    zero converts) via coalesced sendb/recvb index loads (1 dependent level).
//  - ef part unchanged semantics: eidb -> f32 row gather + convert (kept f32
//    to avoid +51 MB workspace for a compacted f16 copy).
//  - per-tile lane-loads 1280 -> 768; f32->f16 converts 5120 -> 1024.
// Staging loop stays rolled/variable-trip with intra-row-contiguous lanes
// (R8/R9: restructures blow FETCH to 450-514 MB — do NOT unroll/split it).
// Grid 512 (measured optimum; 1024 thrashes L2 — R12). XCD-chunked tiles.
// ============================================================================
__global__ __launch_bounds__(512, 4) void edge_mlp_mfma(
    const f16* __restrict__ nf16, const float* __restrict__ ef,
    const f16* __restrict__ F1, const f16* __restrict__ F2,
    const float* __restrict__ b1, const float* __restrict__ b2,
    const float* __restrict__ wg, const float* __restrict__ bg,
    const int* __restrict__ sendb, const int* __restrict__ recvb,
    const int* __restrict__ eidb, const int* __restrict__ cnt,
    f16* __restrict__ msg_out, float* __restrict__ evals)
{
    __shared__ __align__(16) f16 XF[2][10][64][8];  // 20 KB (double buffer)
    __shared__ __align__(16) f16 HB[16][64][8];     // 16 KB
    __shared__ __align__(16) f16 msgt[32][136];     // 8.5 KB
    __shared__ float lpart[8][32];

    const int tid  = threadIdx.x;
    const int wv   = tid >> 6;
    const int lane = tid & 63;
    const int q    = lane >> 4;
    const int li   = lane & 15;
    const int cntv   = cnt[0];
    const int ntiles = (cntv + 31) >> 5;

    // XCD-chunked tile assignment (round-robin blockIdx->XCD heuristic):
    const int xcd   = blockIdx.x & 7;
    const int bslot = blockIdx.x >> 3;
    const int tstep = gridDim.x >> 3;          // blocks per XCD
    const int T8    = (ntiles + 7) >> 3;
    const int tend  = min((xcd + 1) * T8, ntiles);
    const int t0    = xcd * T8 + bslot;

    // stationary weight fragments: W1 2 col-tiles + W2 1 col-tile per wave
    f16x8 w1[2][5], w2[8];
    #pragma unroll
    for (int ntl = 0; ntl < 2; ++ntl)
        #pragma unroll
        for (int ks = 0; ks < 5; ++ks)
            w1[ntl][ks] = *(const f16x8*)(F1 + (((size_t)(ks * 16 + 2 * wv + ntl)) * 64 + lane) * 8);
    #pragma unroll
    for (int ks = 0; ks < 8; ++ks)
        w2[ks] = *(const f16x8*)(F2 + (((size_t)(ks * 8 + wv)) * 64 + lane) * 8);

    const float4 ba  = *(const float4*)&b1[wv * 32 + q * 4];
    const float4 bb  = *(const float4*)&b1[wv * 32 + 16 + q * 4];
    const float4 bc  = *(const float4*)&b2[wv * 16 + q * 4];
    const float4 wg4 = *(const float4*)&wg[wv * 16 + q * 4];
    const float  bgv = bg[0];

    // ---- prologue: stage first tile into XF[0] ----
    if (t0 < tend) {
        const int e0p = t0 * 32;
        f16 (*XFd)[64][8] = XF[0];
        for (int idx = tid; idx < 768; idx += 512) {
            int e = idx / 24, g = idx - e * 24;
            int cp = e0p + e;
            if (g < 16) {
                int node = (g < 8) ? sendb[cp] : recvb[cp];
                f16x8 h = *(const f16x8*)(nf16 + (size_t)node * 64 + (g & 7) * 8);
                int slt = (e >> 4) * 5 + (g >> 2);
                int ln  = (e & 15) + 16 * (g & 3);
                *(f16x8*)&XFd[slt][ln][0] = h;
            } else {
                int eid = eidb[cp];
                float4 v = ((const float4*)ef)[(size_t)eid * 8 + (g - 16)];
                int k0  = 128 + (g - 16) * 4;
                int slt = (e >> 4) * 5 + 4;
                int ln  = (e & 15) + 16 * ((k0 & 31) >> 3);
                int j0  = k0 & 7;
                f16x4 h;
                h.x = (f16)v.x; h.y = (f16)v.y; h.z = (f16)v.z; h.w = (f16)v.w;
                *(f16x4*)&XFd[slt][ln][j0] = h;
            }
        }
    }
    __syncthreads();

    int p = 0;
    for (int t = t0; t < tend; t += tstep) {
        const int e0 = t * 32;
        const int tn = t + tstep;

        // ---- stage NEXT tile into XF[p^1] — no barrier before layer1 ----
        if (tn < tend) {
            const int e0n = tn * 32;
            f16 (*XFd)[64][8] = XF[p ^ 1];
            for (int idx = tid; idx < 768; idx += 512) {
                int e = idx / 24, g = idx - e * 24;
                int cp = e0n + e;
                if (g < 16) {
                    int node = (g < 8) ? sendb[cp] : recvb[cp];
                    f16x8 h = *(const f16x8*)(nf16 + (size_t)node * 64 + (g & 7) * 8);
                    int slt = (e >> 4) * 5 + (g >> 2);
                    int ln  = (e & 15) + 16 * (g & 3);
                    *(f16x8*)&XFd[slt][ln][0] = h;
                } else {
                    int eid = eidb[cp];
                    float4 v = ((const float4*)ef)[(size_t)eid * 8 + (g - 16)];
                    int k0  = 128 + (g - 16) * 4;
                    int slt = (e >> 4) * 5 + 4;
                    int ln  = (e & 15) + 16 * ((k0 & 31) >> 3);
                    int j0  = k0 & 7;
                    f16x4 h;
                    h.x = (f16)v.x; h.y = (f16)v.y; h.z = (f16)v.z; h.w = (f16)v.w;
                    *(f16x4*)&XFd[slt][ln][j0] = h;
                }
            }
        }

        // ---- layer 1: h[col][edge] = W1^T x^T (from XF[p]) ----
        f32x4 acc[2][2];   // [eh][ntl]
        acc[0][0] = f32x4{ba.x, ba.y, ba.z, ba.w}; acc[1][0] = acc[0][0];
        acc[0][1] = f32x4{bb.x, bb.y, bb.z, bb.w}; acc[1][1] = acc[0][1];
        #pragma unroll
        for (int ks = 0; ks < 5; ++ks)
            #pragma unroll
            for (int eh = 0; eh < 2; ++eh) {
                f16x8 xh = *(const f16x8*)XF[p][eh * 5 + ks][lane];
                acc[eh][0] = __builtin_amdgcn_mfma_f32_16x16x32_f16(w1[0][ks], xh, acc[eh][0], 0, 0, 0);
                acc[eh][1] = __builtin_amdgcn_mfma_f32_16x16x32_f16(w1[1][ks], xh, acc[eh][1], 0, 0, 0);
            }
        // relu + stash h as layer-2 B frags
        #pragma unroll
        for (int eh = 0; eh < 2; ++eh)
            #pragma unroll
            for (int ntl = 0; ntl < 2; ++ntl) {
                f16x4 hv;
                hv.x = (f16)fmaxf(acc[eh][ntl][0], 0.f);
                hv.y = (f16)fmaxf(acc[eh][ntl][1], 0.f);
                hv.z = (f16)fmaxf(acc[eh][ntl][2], 0.f);
                hv.w = (f16)fmaxf(acc[eh][ntl][3], 0.f);
                int l2 = li + 16 * (2 * ntl + (q >> 1));
                int j0 = (q & 1) * 4;
                *(f16x4*)&HB[eh * 8 + wv][l2][j0] = hv;
            }
        __syncthreads();   // B1: HB ready; XF[p^1] staged

        // ---- layer 2: msg[col][edge] = W2^T h^T ----
        f32x4 acc2[2];
        acc2[0] = f32x4{bc.x, bc.y, bc.z, bc.w}; acc2[1] = acc2[0];
        #pragma unroll
        for (int ks2 = 0; ks2 < 8; ++ks2)
            #pragma unroll
            for (int eh = 0; eh < 2; ++eh) {
                f16x8 hh = *(const f16x8*)HB[eh * 8 + ks2][lane];
                acc2[eh] = __builtin_amdgcn_mfma_f32_16x16x32_f16(w2[ks2], hh, acc2[eh], 0, 0, 0);
            }
        // relu + gate partial + msg stash
        {
            float pr[2];
            #pragma unroll
            for (int eh = 0; eh < 2; ++eh) {
                float v0 = fmaxf(acc2[eh][0], 0.f);
                float v1 = fmaxf(acc2[eh][1], 0.f);
                float v2 = fmaxf(acc2[eh][2], 0.f);
                float v3 = fmaxf(acc2[eh][3], 0.f);
                f16x4 mm;
                mm.x = (f16)v0; mm.y = (f16)v1; mm.z = (f16)v2; mm.w = (f16)v3;
                *(f16x4*)&msgt[eh * 16 + li][wv * 16 + q * 4] = mm;
                float pp = v0 * wg4.x + v1 * wg4.y + v2 * wg4.z + v3 * wg4.w;
                pp += __shfl_xor(pp, 16, 64);
                pp += __shfl_xor(pp, 32, 64);
                pr[eh] = pp;
            }
            if (lane < 16) {
                lpart[wv][li]      = pr[0];
                lpart[wv][16 + li] = pr[1];
            }
        }
        __syncthreads();   // B2: msgt/lpart ready

        // ---- writeback: coalesced msg rows + evals = exp(logit) ----
        {
            int row = tid >> 4, cg = tid & 15;
            *(uint4*)(msg_out + (size_t)(e0 + row) * 128 + cg * 8) =
                *(const uint4*)&msgt[row][cg * 8];
        }
        if (tid < 32) {
            float s2 = bgv;
            #pragma unroll
            for (int w = 0; w < 8; ++w) s2 += lpart[w][tid];
            evals[e0 + tid] = expf(s2);   // softmax shift-invariant; |logit|~O(5)
        }
        p ^= 1;
    }
}

// ============================================================================
// Fused CSR softmax-aggregation + agent MLP. 1024 thr, 32 receivers/block.
// Aggregation: 32 threads per receiver, 4 cols each (8 B/lane), sequential
// bucket rows. R13: 4-way software-pipelined inner loop.
// ============================================================================
__global__ __launch_bounds__(1024, 4) void agg_agent_mfma(
    const int* __restrict__ off, const float* __restrict__ evals,
    const f16* __restrict__ msg,
    const f16* __restrict__ F3, const f16* __restrict__ F4,
    const float* __restrict__ bh1, const float* __restrict__ bh2,
    const float* __restrict__ Wout, const float* __restrict__ bout,
    float* __restrict__ out)
{
    __shared__ __align__(16) f16 XA[8][64][8];     // 8 KB
    __shared__ __align__(16) f16 HB2[16][64][8];   // 16 KB
    __shared__ float lpart[16][32];

    const int tid  = threadIdx.x;
    const int wv   = tid >> 6;
    const int lane = tid & 63;
    const int q    = lane >> 4;
    const int li   = lane & 15;
    const int a0i  = blockIdx.x * 32;

    // ---- aggregation straight into XA fragment layout ----
    {
        int g = tid >> 5, c = tid & 31;   // receiver a0i+g, cols [c*4, c*4+4)
        int r = a0i + g;
        float den = 1e-9f;
        float4 acc = make_float4(0.f, 0.f, 0.f, 0.f);
        if (r < N_AGENTS) {
            int beg = off[r], end = off[r + 1];
            const u64* mp = (const u64*)(msg + (size_t)beg * 128) + c;
            int pp = beg;
            for (; pp + 3 < end; pp += 4, mp += 128) {
                float e0 = evals[pp], e1 = evals[pp + 1];
                float e2 = evals[pp + 2], e3 = evals[pp + 3];
                u64 u0 = mp[0], u1 = mp[32], u2 = mp[64], u3 = mp[96];
                den += (e0 + e1) + (e2 + e3);
                union { u64 u; f16 h[4]; } c0, c1, c2, c3;
                c0.u = u0; c1.u = u1; c2.u = u2; c3.u = u3;
                acc.x = fmaf(e3, (float)c3.h[0], fmaf(e2, (float)c2.h[0],
                        fmaf(e1, (float)c1.h[0], fmaf(e0, (float)c0.h[0], acc.x))));
                acc.y = fmaf(e3, (float)c3.h[1], fmaf(e2, (float)c2.h[1],
                        fmaf(e1, (float)c1.h[1], fmaf(e0, (float)c0.h[1], acc.y))));
                acc.z = fmaf(e3, (float)c3.h[2], fmaf(e2, (float)c2.h[2],
                        fmaf(e1, (float)c1.h[2], fmaf(e0, (float)c0.h[2], acc.z))));
                acc.w = fmaf(e3, (float)c3.h[3], fmaf(e2, (float)c2.h[3],
                        fmaf(e1, (float)c1.h[3], fmaf(e0, (float)c0.h[3], acc.w))));
            }
            for (; pp < end; ++pp, mp += 32) {
                float e = evals[pp];
                den += e;
                union { u64 u; f16 h[4]; } cv; cv.u = *mp;
                acc.x = fmaf(e, (float)cv.h[0], acc.x);
                acc.y = fmaf(e, (float)cv.h[1], acc.y);
                acc.z = fmaf(e, (float)cv.h[2], acc.z);
                acc.w = fmaf(e, (float)cv.h[3], acc.w);
            }
        }
        float inv = 1.0f / den;
        int k0   = c * 4;
        int slot = (g >> 4) * 4 + (k0 >> 5);
        int ln   = (g & 15) + 16 * ((k0 & 31) >> 3);
        int j0   = k0 & 7;
        f16x4 h;
        h.x = (f16)(acc.x * inv); h.y = (f16)(acc.y * inv);
        h.z = (f16)(acc.z * inv); h.w = (f16)(acc.w * inv);
        *(f16x4*)&XA[slot][ln][j0] = h;
    }
    __syncthreads();

    // ---- weight fragments + layer 1 ----
    f16x8 wh1[4], wh2[8];
    #pragma unroll
    for (int ks = 0; ks < 4; ++ks)
        wh1[ks] = *(const f16x8*)(F3 + (((size_t)(ks * 16 + wv)) * 64 + lane) * 8);
    #pragma unroll
    for (int ks = 0; ks < 8; ++ks)
        wh2[ks] = *(const f16x8*)(F4 + (((size_t)(ks * 16 + wv)) * 64 + lane) * 8);

    f32x4 acc[2] = {};
    #pragma unroll
    for (int ks = 0; ks < 4; ++ks)
        #pragma unroll
        for (int eh = 0; eh < 2; ++eh) {
            f16x8 xh = *(const f16x8*)XA[eh * 4 + ks][lane];
            acc[eh] = __builtin_amdgcn_mfma_f32_16x16x32_f16(wh1[ks], xh, acc[eh], 0, 0, 0);
        }
    {
        const float4 b1v = ((const float4*)bh1)[wv * 4 + q];
        #pragma unroll
        for (int eh = 0; eh < 2; ++eh) {
            f16x4 hv;
            hv.x = (f16)fmaxf(acc[eh][0] + b1v.x, 0.f);
            hv.y = (f16)fmaxf(acc[eh][1] + b1v.y, 0.f);
            hv.z = (f16)fmaxf(acc[eh][2] + b1v.z, 0.f);
            hv.w = (f16)fmaxf(acc[eh][3] + b1v.w, 0.f);
            int l2 = li + 16 * ((wv & 1) * 2 + (q >> 1));
            int j0 = (q & 1) * 4;
            *(f16x4*)&HB2[eh * 8 + (wv >> 1)][l2][j0] = hv;
        }
    }
    __syncthreads();

    // ---- layer 2 + output partial ----
    f32x4 acc2[2] = {};
    #pragma unroll
    for (int ks2 = 0; ks2 < 8; ++ks2)
        #pragma unroll
        for (int eh = 0; eh < 2; ++eh) {
            f16x8 hh = *(const f16x8*)HB2[eh * 8 + ks2][lane];
            acc2[eh] = __builtin_amdgcn_mfma_f32_16x16x32_f16(wh2[ks2], hh, acc2[eh], 0, 0, 0);
        }
    {
        const float4 b2v = ((const float4*)bh2)[wv * 4 + q];
        const float4 wo4 = ((const float4*)Wout)[wv * 4 + q];
        float pr[2];
        #pragma unroll
        for (int eh = 0; eh < 2; ++eh) {
            float pp = fmaxf(acc2[eh][0] + b2v.x, 0.f) * wo4.x
                     + fmaxf(acc2[eh][1] + b2v.y, 0.f) * wo4.y
                     + fmaxf(acc2[eh][2] + b2v.z, 0.f) * wo4.z
                     + fmaxf(acc2[eh][3] + b2v.w, 0.f) * wo4.w;
            pp += __shfl_xor(pp, 16, 64);
            pp += __shfl_xor(pp, 32, 64);
            pr[eh] = pp;
        }
        if (lane < 16) {
            lpart[wv][li]      = pr[0];
            lpart[wv][16 + li] = pr[1];
        }
    }
    __syncthreads();

    if (tid < 32 && a0i + tid < N_AGENTS) {
        float s = bout[0];
        #pragma unroll
        for (int w = 0; w < 16; ++w) s += lpart[w][tid];
        out[a0i + tid] = tanhf(s);
    }
}

// ============================================================================
extern "C" void kernel_launch(void* const* d_in, const int* in_sizes, int n_in,
                              void* d_out, int out_size, void* d_ws, size_t ws_size,
                              hipStream_t stream)
{
    const float* nf   = (const float*)d_in[0];
    const float* ef   = (const float*)d_in[1];
    const float* W1   = (const float*)d_in[2];
    const float* b1   = (const float*)d_in[3];
    const float* W2   = (const float*)d_in[4];
    const float* b2   = (const float*)d_in[5];
    const float* wg   = (const float*)d_in[6];
    const float* bg   = (const float*)d_in[7];
    const float* Wh1  = (const float*)d_in[8];
    const float* bh1  = (const float*)d_in[9];
    const float* Wh2  = (const float*)d_in[10];
    const float* bh2  = (const float*)d_in[11];
    const float* Wout = (const float*)d_in[12];
    const float* bout = (const float*)d_in[13];
    const int*   send = (const int*)d_in[14];
    const int*   recv = (const int*)d_in[15];

    // workspace: [deg|eidb|sendb|recvb] zeroed (tail indices of the last
    // padded tile must gather row 0, not garbage), then the rest
    char* ws = (char*)d_ws;
    int* deg    = (int*)ws;            ws += (size_t)N_AGENTS * 4;
    int* eidb   = (int*)ws;            ws += (size_t)EPAD * 4;
    int* sendb  = (int*)ws;            ws += (size_t)EPAD * 4;
    int* recvb  = (int*)ws;            ws += (size_t)EPAD * 4;
    size_t zero_bytes = (size_t)(ws - (char*)d_ws);
    int* rankb  = (int*)ws;            ws += (size_t)N_EDGES * 4;
    int* off    = (int*)ws;            ws += (size_t)(N_AGENTS + 8) * 4;
    float* evals = (float*)ws;         ws += (size_t)EPAD * 4;
    f16* nf16   = (f16*)ws;            ws += (size_t)N_NODES * ND * 2;
    f16* F1     = (f16*)ws;            ws += (size_t)160 * 256 * 2;
    f16* F2     = (f16*)ws;            ws += (size_t)256 * 128 * 2;
    f16* F3     = (f16*)ws;            ws += (size_t)128 * 256 * 2;
    f16* F4     = (f16*)ws;            ws += (size_t)256 * 256 * 2;
    f16* msg    = (f16*)ws;

    hipMemsetAsync(d_ws, 0, zero_bytes, stream);

    pack_weights<<<84, 256, 0, stream>>>(W1, W2, Wh1, Wh2, F1, F2, F3, F4);
    compact_kernel<<<N_EDGES / 256, 256, 0, stream>>>(
        recv, nf, nf16, rankb, deg);
    prefix_kernel<<<1, 1024, 0, stream>>>(deg, off);
    scatter_kernel<<<N_EDGES / 256, 256, 0, stream>>>(
        recv, send, rankb, off, eidb, sendb, recvb);
    edge_mlp_mfma<<<512, 512, 0, stream>>>(
        nf16, ef, F1, F2, b1, b2, wg, bg, sendb, recvb, eidb, off + N_AGENTS, msg, evals);
    agg_agent_mfma<<<(N_AGENTS + 31) / 32, 1024, 0, stream>>>(
        off, evals, msg, F3, F4, bh1, bh2, Wout, bout, (float*)d_out);
}